// Round 17
// baseline (75.047 us; speedup 1.0000x reference)
//
#include <hip/hip_runtime.h>

typedef float f32x4 __attribute__((ext_vector_type(4)));
typedef short bf16x8 __attribute__((ext_vector_type(8)));
typedef unsigned int u32;
typedef unsigned short u16;

constexpr int T_ = 32768;
constexpr int D_ = 2048;
constexpr int E_ = 64;
constexpr int KSEL = 6;
constexpr float ROUTE_SCALE_ = 1.0f;

constexpr int ROWS = 64;            // rows per block; 8 waves = 4 rg x 2 K-halves
constexpr int DK = 32;              // k per chunk
constexpr int NCHH = 1024 / DK;     // 32 chunks per K-half
constexpr int WBUF = 12288;         // one W chunk: 12 frags x 1KB
constexpr int HSTRIDE = 3 * WBUF;   // per-half TRIPLE buffer; LDS total = 73728
constexpr int SLSTR = 66;           // padded row-stride of SL[half][e][row]

__device__ __forceinline__ u16 f2bf(float f) {
  u32 u = __float_as_uint(f);
  return (u16)((u + 0x7fffu + ((u >> 16) & 1u)) >> 16);
}
__device__ __forceinline__ float bf2f(u16 h) { return __uint_as_float(((u32)h) << 16); }

// ---- W pre-split (bytes identical to R10/R12/R16) ----
__global__ void wsplit_kernel(const float* __restrict__ W, char* __restrict__ ws) {
  int g = blockIdx.x * 256 + threadIdx.x;
  if (g >= 64 * 256) return;                   // 16384 threads
  int lane = g & 63, nfq = (g >> 6) & 3, c2 = g >> 8;
  int e = nfq * 16 + (lane & 15);
  int k0 = c2 * 32 + ((lane >> 4) << 3);
  const float* src = W + (size_t)e * D_ + k0;
  f32x4 a0 = *(const f32x4*)src;
  f32x4 a1 = *(const f32x4*)(src + 4);
  float f[8] = {a0.x, a0.y, a0.z, a0.w, a1.x, a1.y, a1.z, a1.w};
  bf16x8 h, m, l;
#pragma unroll
  for (int j = 0; j < 8; ++j) {
    u16 hb = f2bf(f[j]); float r1 = f[j] - bf2f(hb);   // exact
    u16 mb = f2bf(r1);   float r2 = r1 - bf2f(mb);     // exact
    u16 lb = f2bf(r2);
    h[j] = (short)hb; m[j] = (short)mb; l[j] = (short)lb;
  }
  char* dst = ws + (size_t)c2 * WBUF + (size_t)(nfq * 3) * 1024 + lane * 16;
  *(bf16x8*)(dst)        = h;
  *(bf16x8*)(dst + 1024) = m;
  *(bf16x8*)(dst + 2048) = l;
}

__device__ __forceinline__ void gload16(const void* g, void* l) {
  __builtin_amdgcn_global_load_lds(
      (const __attribute__((address_space(1))) void*)g,
      (__attribute__((address_space(3))) void*)l, 16, 0, 0);
}

#define PIN asm volatile("" ::: "memory")
#define WAITV(N) asm volatile("s_waitcnt vmcnt(" #N ")" ::: "memory")
#define BAR __builtin_amdgcn_s_barrier()

__launch_bounds__(512, 4)
__global__ void gate_kernel(const float* __restrict__ x, const char* __restrict__ ws,
                            float* __restrict__ out) {
  __shared__ __align__(16) char sm[2 * HSTRIDE];   // 73728 B -> 2 blocks/CU

  const int tid = threadIdx.x;
  const int lane = tid & 63;
  const int wv = tid >> 6;                 // 0..7
  const int half = wv >> 2;                // K-half: k in [half*1024, +1024)
  const int wl = wv & 3;                   // row group: rows [wl*16, wl*16+16)
  const int r0 = blockIdx.x * ROWS;

  const float* xp = x + (size_t)(r0 + wl * 16 + (lane & 15)) * D_
                      + half * 1024 + ((lane >> 4) << 3);

  f32x4 x0[2], x1[2], x2[2], x3[2];        // 4 static x banks; chunk c -> bank c&3

#define XLOAD(BANK, C)                                            \
  { const float* p_ = xp + (size_t)(C) * DK;                      \
    BANK[0] = *(const f32x4*)(p_); BANK[1] = *(const f32x4*)(p_ + 4); }

  // stage chunk c2 of this half into explicit buffer DBUF (12KB; identity mapping).
  // LDS dst wave-uniform (HW adds lane*16); global src per-lane.
  auto wgload = [&](int c2, char* dbuf) {
    const char* src = ws + (size_t)(half * NCHH + c2) * WBUF
                         + (size_t)(wl * 64 + lane) * 16;               // per-lane
    char* dstb = dbuf + (size_t)(wl * 64) * 16;                         // wave-uniform
#pragma unroll
    for (int it = 0; it < 3; ++it)
      gload16(src + it * 4096, dstb + it * 4096);
  };

  f32x4 acc[4] = {};                       // 4 expert-quadrants x 4 regs

  // chain identical to R12/R16 -> bit-identical logits (FROZEN)
#define STEP(BANK, RBUF)                                                       \
  {                                                                            \
    bf16x8 ah, am, al;                                                         \
    {                                                                          \
      f32x4 a0 = BANK[0], a1 = BANK[1];                                        \
      float f[8] = {a0.x, a0.y, a0.z, a0.w, a1.x, a1.y, a1.z, a1.w};           \
      _Pragma("unroll")                                                        \
      for (int j = 0; j < 8; ++j) {                                            \
        float v = f[j];                                                        \
        u32 uh = __float_as_uint(v) & 0xffff0000u;                             \
        float r1 = v - __uint_as_float(uh);                                    \
        u32 um = __float_as_uint(r1) & 0xffff0000u;                            \
        float r2 = r1 - __uint_as_float(um);                                   \
        u32 ul = __float_as_uint(r2);                                          \
        ah[j] = (short)(uh >> 16);                                             \
        am[j] = (short)(um >> 16);                                             \
        al[j] = (short)(ul >> 16);                                             \
      }                                                                        \
    }                                                                          \
    const char* wb = (RBUF) + lane * 16;                                       \
    _Pragma("unroll")                                                          \
    for (int n = 0; n < 4; ++n) {                                              \
      const char* fb = wb + (size_t)(n * 3) * 1024;                            \
      bf16x8 bh = *(const bf16x8*)(fb);                                        \
      bf16x8 bm = *(const bf16x8*)(fb + 1024);                                 \
      bf16x8 bl = *(const bf16x8*)(fb + 2048);                                 \
      f32x4 c_ = acc[n];                                                       \
      c_ = __builtin_amdgcn_mfma_f32_16x16x32_bf16(al, bh, c_, 0, 0, 0);       \
      c_ = __builtin_amdgcn_mfma_f32_16x16x32_bf16(am, bm, c_, 0, 0, 0);       \
      c_ = __builtin_amdgcn_mfma_f32_16x16x32_bf16(ah, bl, c_, 0, 0, 0);       \
      c_ = __builtin_amdgcn_mfma_f32_16x16x32_bf16(am, bh, c_, 0, 0, 0);       \
      c_ = __builtin_amdgcn_mfma_f32_16x16x32_bf16(ah, bm, c_, 0, 0, 0);       \
      c_ = __builtin_amdgcn_mfma_f32_16x16x32_bf16(ah, bh, c_, 0, 0, 0);       \
      acc[n] = c_;                                                             \
    }                                                                          \
  }

  // rotating triple-buffer pointers for this half
  char* base = sm + half * HSTRIDE;
  char* r0b = base;
  char* r1b = base + WBUF;
  char* r2b = base + 2 * WBUF;

  // ---- prologue: wg(0), then {xl0, xl1, wg(1)}; vmcnt(7) drains exactly wg(0) ----
  wgload(0, r0b); PIN;
  XLOAD(x0, 0) XLOAD(x1, 1) wgload(1, r1b); PIN;
  WAITV(7); BAR;

  // ---- main loop: 7 groups x 4 phases (c = 0..27); never drain vmcnt to 0.
  // Each phase: wgload(c+2) [pin] xload(c+2) STEP(c) vmcnt(7) barrier.
  // vmcnt(7) keeps {xl(c+1),wg(c+2),xl(c+2)} in flight, drains wg(c+1). ----
  for (int g = 0; g < 7; ++g) {
    const int cc = g * 4;
    wgload(cc + 2, r2b); PIN; XLOAD(x2, cc + 2) STEP(x0, r0b) WAITV(7); BAR;
    wgload(cc + 3, r0b); PIN; XLOAD(x3, cc + 3) STEP(x1, r1b) WAITV(7); BAR;
    wgload(cc + 4, r1b); PIN; XLOAD(x0, cc + 4) STEP(x2, r2b) WAITV(7); BAR;
    wgload(cc + 5, r2b); PIN; XLOAD(x1, cc + 5) STEP(x3, r0b) WAITV(7); BAR;
    char* t = r0b; r0b = r1b; r1b = r2b; r2b = t;   // bufs for cc+4, cc+5, cc+6
  }

  // ---- peeled tail: c = 28, 29, 30, 31 ----
  wgload(30, r2b); PIN; XLOAD(x2, 30) STEP(x0, r0b) WAITV(7); BAR;   // c=28
  wgload(31, r0b); PIN; XLOAD(x3, 31) STEP(x1, r1b) WAITV(7); BAR;   // c=29
  STEP(x2, r2b) WAITV(2); BAR;                                        // c=30
  STEP(x3, r0b)                                                       // c=31

  // ---- partial logits TRANSPOSED to LDS: SL[half][e][row], stride 66 ----
  __syncthreads();                         // full drain; wbuf region reused as SL
  float* SL = (float*)sm;
#pragma unroll
  for (int n = 0; n < 4; ++n)
#pragma unroll
    for (int j = 0; j < 4; ++j) {
      int r = wl * 16 + ((lane >> 4) << 2) + j;
      int e = n * 16 + (lane & 15);
      SL[half * (E_ * SLSTR) + e * SLSTR + r] = acc[n][j];
    }
  __syncthreads();

  // ---- softmax-free top-k (monotone softmax => top-k by logit; strict > +
  // ascending-e scan == jax tie-to-lower-index). wave 0, lane = row. ----
  if (wv == 0) {
    float tv[KSEL], ti[KSEL];
#pragma unroll
    for (int kk = 0; kk < KSEL; ++kk) { tv[kk] = -3.4e38f; ti[kk] = 0.f; }
    for (int e = 0; e < E_; ++e) {
      float v = SL[e * SLSTR + lane] + SL[E_ * SLSTR + e * SLSTR + lane];
      float vi = (float)e;
#pragma unroll
      for (int kk = 0; kk < KSEL; ++kk) {
        bool c = v > tv[kk];
        float nv = c ? v : tv[kk];  float dv = c ? tv[kk] : v;
        float ni = c ? vi : ti[kk]; float di = c ? ti[kk] : vi;
        tv[kk] = nv; v = dv; ti[kk] = ni; vi = di;
      }
    }
    const int rg = r0 + lane;
    float* outI = out;
    float* outW = out + (size_t)T_ * KSEL;
#pragma unroll
    for (int kk = 0; kk < KSEL; ++kk) {
      outI[(size_t)rg * KSEL + kk] = ti[kk];
      outW[(size_t)rg * KSEL + kk] = tv[kk] * ROUTE_SCALE_;
    }
  }
#undef XLOAD
#undef STEP
}

extern "C" void kernel_launch(void* const* d_in, const int* in_sizes, int n_in,
                              void* d_out, int out_size, void* d_ws, size_t ws_size,
                              hipStream_t stream) {
  const float* x = (const float*)d_in[0];
  const float* W = (const float*)d_in[1];
  char* ws = (char*)d_ws;                  // 64 * 12288 = 786432 bytes
  float* out = (float*)d_out;
  wsplit_kernel<<<dim3(64), dim3(256), 0, stream>>>(W, ws);
  gate_kernel<<<dim3(T_ / ROWS), dim3(512), 0, stream>>>(x, ws, out);
}